// Round 1
// 838.135 us; speedup vs baseline: 1.6277x; 1.6277x over previous
//
#include <hip/hip_runtime.h>
#include <hip/hip_bf16.h>
#include <hip/hip_fp16.h>

typedef __hip_bfloat16 bf16_t;

#define NU 100000
#define NI 100000
#define NB_ 5000
#define NC_ 2000
#define NR_ 50000
#define NE 600000
#define NEB 100000
#define NEC 200000
#define NER 400000
#define NPERM (2 * NE + NEB + NEC + NER)   // 1,900,000
#define NRELE (NEB + NEC + NER)            // 700,000
#define NALL (NE + NRELE)
#define SCAN_N (2 * NU + NI + 1)
#define SCAN_CHUNK 2048
#define SCAN_NCHUNK ((SCAN_N + SCAN_CHUNK - 1) / SCAN_CHUNK)
#define VBLK ((NU + 3) / 4)                // gather blocks per phase (NU==NI)

typedef __attribute__((ext_vector_type(8))) short short8;
typedef __attribute__((ext_vector_type(4))) float f32x4;

__device__ __forceinline__ float b2f(bf16_t x) { return __bfloat162float(x); }
__device__ __forceinline__ float sane(float x) { return isfinite(x) ? x : 0.f; }
__device__ __forceinline__ unsigned short f2bu(float x) {
    union { bf16_t b; unsigned short u; } c; c.b = __float2bfloat16(x); return c.u;
}

// dual-dtype load/store: external float tensors are f32 or bf16, per runtime flag
__device__ __forceinline__ float ldf(const void* p, size_t i, int f32) {
    return f32 ? ((const float*)p)[i] : __bfloat162float(((const bf16_t*)p)[i]);
}
__device__ __forceinline__ void stf(void* p, size_t i, float v, int f32) {
    if (f32) ((float*)p)[i] = v;
    else     ((bf16_t*)p)[i] = __float2bfloat16(v);
}

// ---- dtype probe: basis_freq[0] == 1.0f exactly; f32 word = 0x3F800000 ----
__global__ void detect_dtype(const unsigned int* w, int* flag) {
    if (threadIdx.x == 0 && blockIdx.x == 0) *flag = (w[0] == 0x3F800000u) ? 1 : 0;
}

// ---- wcomb_r = W_feat_r @ Wr_r (bf16 out, internal) ----
__global__ void combine_w(const void* Wb, const void* Wr0,
                          const void* Wc, const void* Wr1,
                          const void* Wr, const void* Wr2,
                          bf16_t* out, const int* flagp) {
    int f = *flagp;
    const void* A = blockIdx.x == 0 ? Wb : (blockIdx.x == 1 ? Wc : Wr);
    const void* B = blockIdx.x == 0 ? Wr0 : (blockIdx.x == 1 ? Wr1 : Wr2);
    bf16_t* O = out + (size_t)blockIdx.x * 4096;
    for (int idx = threadIdx.x; idx < 4096; idx += blockDim.x) {
        int i = idx >> 6, j = idx & 63;
        float acc = 0.f;
        for (int k = 0; k < 64; ++k)
            acc = fmaf(ldf(A, i * 64 + k, f), ldf(B, k * 64 + j, f), acc);
        O[idx] = __float2bfloat16(acc);
    }
}

// ============================================================================
// Generic MFMA GEMM: out = act(A[M,K] @ W[K,64] + bias), K in {64,128}.
// Block = 256 thr = 4 waves; 64 rows per block, wave handles a 16-row strip.
// MFMA 16x16x32 bf16. Layouts (HW-verified per guide):
//   A frag:  lane holds A[m0+(lane&15)][kk + (lane>>4)*8 + j], j=0..7
//   B frag:  lane holds W[kk + (lane>>4)*8 + j][n0 + (lane&15)]
//   C/D:     row = m0 + (lane>>4)*4 + reg, col = n0 + (lane&15)
// W staged in LDS pre-swizzled so each B frag is one ds_read_b128.
// mode 0: out = bf16 internal, no bias/act. mode 1: out = external dtype,
//         v += hext(+relb); elu; store at row+orow0.
// ============================================================================
__global__ __launch_bounds__(256) void gemm_n64(
    const void* __restrict__ A, int a_internal,
    const void* __restrict__ W, int w_internal,
    const void* __restrict__ hext, const bf16_t* __restrict__ relb,
    void* __restrict__ out, int out_mode, int orow0,
    int M, int K, const int* flagp) {
    __shared__ short WL[128 * 64];   // 16 KB max (K*64 used)
    int f = *flagp;
    int a_f32 = a_internal ? 0 : f;
    int w_f32 = w_internal ? 0 : f;
    for (int i = threadIdx.x; i < K * 64; i += 256) {
        int j = i & 7, ln = (i >> 3) & 63, p = i >> 9;
        int kk4 = p >> 2, n0t = p & 3;
        int srow = kk4 * 32 + (ln >> 4) * 8 + j;
        int scol = n0t * 16 + (ln & 15);
        float wv = w_f32 ? ((const float*)W)[srow * 64 + scol]
                         : b2f(((const bf16_t*)W)[srow * 64 + scol]);
        WL[i] = (short)f2bu(wv);
    }
    __syncthreads();
    int lane = threadIdx.x & 63;
    int wv = threadIdx.x >> 6;
    int q = lane >> 4, nl = lane & 15;
    int m0 = blockIdx.x * 64 + wv * 16;
    if (m0 >= M) return;
    int arow = m0 + nl; if (arow >= M) arow = M - 1;
    f32x4 acc[4];
#pragma unroll
    for (int t = 0; t < 4; ++t) acc[t] = (f32x4){0.f, 0.f, 0.f, 0.f};
    int KK = K >> 5;
    for (int kk4 = 0; kk4 < KK; ++kk4) {
        short8 af;
        size_t abase = (size_t)arow * K + kk4 * 32 + q * 8;
        if (a_f32) {
            const f32x4* ap = (const f32x4*)((const float*)A + abase);
            f32x4 x0 = ap[0], x1 = ap[1];
#pragma unroll
            for (int j = 0; j < 4; ++j) {
                af[j] = (short)f2bu(x0[j]);
                af[4 + j] = (short)f2bu(x1[j]);
            }
        } else {
            af = *(const short8*)((const bf16_t*)A + abase);
        }
#pragma unroll
        for (int n0t = 0; n0t < 4; ++n0t) {
            short8 bfr = *(const short8*)&WL[(((kk4 << 2) + n0t) * 64 + lane) * 8];
            acc[n0t] = __builtin_amdgcn_mfma_f32_16x16x32_bf16(af, bfr, acc[n0t], 0, 0, 0);
        }
    }
#pragma unroll
    for (int n0t = 0; n0t < 4; ++n0t) {
#pragma unroll
        for (int r = 0; r < 4; ++r) {
            int row = m0 + q * 4 + r;
            if (row >= M) continue;
            int col = n0t * 16 + nl;
            float v = acc[n0t][r];
            if (out_mode == 1) {
                v += ldf(hext, (size_t)row * 64 + col, f);
                if (relb) v += b2f(relb[(size_t)row * 64 + col]);
                v = v > 0.f ? v : expm1f(v);
                stf(out, (size_t)(row + orow0) * 64 + col, sane(v), f);
            } else {
                ((bf16_t*)out)[(size_t)row * 64 + col] = __float2bfloat16(v);
            }
        }
    }
}

// ---- one-launch degree histogram over all edge sets ----
__global__ __launch_bounds__(256) void hist_all(
    const int* __restrict__ e_uid, const int* __restrict__ e_iid,
    const int* __restrict__ eb_dst, const int* __restrict__ ec_dst,
    const int* __restrict__ er_dst, int* __restrict__ deg) {
    int t = blockIdx.x * blockDim.x + threadIdx.x;
    if (t < NE) {
        atomicAdd(deg + e_uid[t], 1);
        atomicAdd(deg + NU + e_iid[t], 1);
    } else if (t < NE + NEB) {
        atomicAdd(deg + 2 * NU + eb_dst[t - NE], 1);
    } else if (t < NE + NEB + NEC) {
        atomicAdd(deg + 2 * NU + ec_dst[t - NE - NEB], 1);
    } else if (t < NALL) {
        atomicAdd(deg + 2 * NU + er_dst[t - NE - NEB - NEC], 1);
    }
}

// ---- exclusive scan over SCAN_N ints ----
__global__ __launch_bounds__(256) void scan1(const int* __restrict__ deg,
                                             int* __restrict__ off,
                                             int* __restrict__ ctot) {
    __shared__ int part[256];
    int base = blockIdx.x * SCAN_CHUNK + threadIdx.x * 8;
    int v[8]; int s = 0;
#pragma unroll
    for (int k = 0; k < 8; ++k) {
        int idx = base + k;
        v[k] = s;
        s += (idx < SCAN_N) ? deg[idx] : 0;
    }
    part[threadIdx.x] = s;
    __syncthreads();
    for (int o = 1; o < 256; o <<= 1) {
        int t = (threadIdx.x >= o) ? part[threadIdx.x - o] : 0;
        __syncthreads();
        part[threadIdx.x] += t;
        __syncthreads();
    }
    int texc = (threadIdx.x == 0) ? 0 : part[threadIdx.x - 1];
#pragma unroll
    for (int k = 0; k < 8; ++k) {
        int idx = base + k;
        if (idx < SCAN_N) off[idx] = texc + v[k];
    }
    if (threadIdx.x == 255) ctot[blockIdx.x] = part[255];
}
__global__ void scan2(const int* __restrict__ ctot, int* __restrict__ coff) {
    if (threadIdx.x == 0 && blockIdx.x == 0) {
        int s = 0;
        for (int i = 0; i < SCAN_NCHUNK; ++i) { coff[i] = s; s += ctot[i]; }
    }
}
__global__ __launch_bounds__(256) void scan3(int* __restrict__ off,
                                             const int* __restrict__ coff) {
    int add = coff[blockIdx.x];
    int base = blockIdx.x * SCAN_CHUNK + threadIdx.x;
#pragma unroll
    for (int k = 0; k < 8; ++k) {
        int idx = base + k * 256;
        if (idx < SCAN_N) off[idx] += add;
    }
}

// ---- wave-per-edge: dots + exp + payload scatter (both directions) ----
// payload: {nbr | pos<<17,  f16(p_long) | f16(p_short)<<16}
// NO LDS staging: u_pos_k / i_pos_k are 12.8 KB each -> L1-resident; a
// coalesced 128B read per edge beats staging 12.8 KB per tiny block.
// Grid-stride (2048 blocks = 8 blocks/CU) amortizes basis/phase loads.
__global__ __launch_bounds__(256) void purchase_edges(
    const bf16_t* __restrict__ uh, const bf16_t* __restrict__ ih,
    const void* __restrict__ u_pos_k, const void* __restrict__ i_pos_k,
    const void* __restrict__ basis_freq, const void* __restrict__ phase,
    const void* __restrict__ e_time,
    const int* __restrict__ e_uid, const int* __restrict__ e_iid,
    const int* __restrict__ pos_u, const int* __restrict__ pos_i,
    int* __restrict__ cur, uint2* __restrict__ perm, const int* flagp) {
    int f = *flagp;
    int lane = threadIdx.x & 63;
    float bfv = ldf(basis_freq, lane, f);
    float phv = ldf(phase, lane, f);
    int w = (blockIdx.x * blockDim.x + threadIdx.x) >> 6;
    int nw = (gridDim.x * blockDim.x) >> 6;
    for (int e = w; e < NE; e += nw) {
        int uid = e_uid[e], iid = e_iid[e], pu = pos_u[e], pi = pos_i[e];
        float t = ldf(e_time, e, f);
        float te = __cosf(fmaf(t, bfv, phv));
        float hu = b2f(uh[(size_t)uid * 64 + lane]);
        float hi = b2f(ih[(size_t)iid * 64 + lane]);
        float pku = ldf(u_pos_k, (size_t)pu * 64 + lane, f);
        float pki = ldf(i_pos_k, (size_t)pi * 64 + lane, f);
        float d_lu = (hi + pku + te) * hu;
        float d_sh = hi * hu;
        float d_li = (hu + pki + te) * hi;
#pragma unroll
        for (int o = 32; o; o >>= 1) {
            d_lu += __shfl_xor(d_lu, o, 64);
            d_sh += __shfl_xor(d_sh, o, 64);
            d_li += __shfl_xor(d_li, o, 64);
        }
        if (lane == 0) {
            float p_lu = __expf(fminf(d_lu * 0.125f, 10.f));   // clamp protects f16 pack
            float p_sh = __expf(fminf(d_sh * 0.125f, 10.f));
            float p_li = __expf(fminf(d_li * 0.125f, 10.f));
            unsigned pkt_u = (unsigned)__half_as_ushort(__float2half(p_lu))
                           | ((unsigned)__half_as_ushort(__float2half(p_sh)) << 16);
            unsigned pkt_i = (unsigned)__half_as_ushort(__float2half(p_li))
                           | ((unsigned)__half_as_ushort(__float2half(p_sh)) << 16);
            int s1 = atomicAdd(cur + uid, 1);
            perm[s1] = make_uint2((unsigned)iid | ((unsigned)pu << 17), pkt_u);
            int s2 = atomicAdd(cur + NU + iid, 1);
            perm[s2] = make_uint2((unsigned)uid | ((unsigned)pi << 17), pkt_i);
        }
    }
}

// ---- relation edge payload scatter (thread per edge) ----
__global__ __launch_bounds__(256) void scatter_rel_all(
    const int* __restrict__ eb_src, const int* __restrict__ eb_dst,
    const int* __restrict__ ec_src, const int* __restrict__ ec_dst,
    const int* __restrict__ er_src, const int* __restrict__ er_dst,
    int* __restrict__ cur, uint2* __restrict__ perm) {
    int t = blockIdx.x * blockDim.x + threadIdx.x;
    if (t < NEB) {
        int p = atomicAdd(cur + 2 * NU + eb_dst[t], 1);
        perm[p] = make_uint2((unsigned)eb_src[t], 0u);
    } else if (t < NEB + NEC) {
        int e = t - NEB;
        int p = atomicAdd(cur + 2 * NU + ec_dst[e], 1);
        perm[p] = make_uint2((unsigned)(ec_src[e] + NB_) | (1u << 17), 0u);
    } else if (t < NRELE) {
        int e = t - NEB - NEC;
        int p = atomicAdd(cur + 2 * NU + er_dst[e], 1);
        perm[p] = make_uint2((unsigned)(er_src[e] + NB_ + NC_) | (2u << 17), 0u);
    }
}

// ---- gather: reduction-free softmax aggregation; writes agg rows (+relb) ----
// NO LDS staging: pos tables (12.8 KB) are L1-resident; read directly,
// software-pipelined with the neighbor-row gather. No barrier needed.
__global__ __launch_bounds__(256) void gather_agg(
    const bf16_t* __restrict__ uh, const bf16_t* __restrict__ ih,
    const void* __restrict__ u_pos, const void* __restrict__ i_pos,
    const int* __restrict__ off, const uint2* __restrict__ perm,
    const bf16_t* __restrict__ fW,
    bf16_t* __restrict__ agg, bf16_t* __restrict__ relb,
    const int* flagp, int phase) {            // phase 0 = user, 1 = item
    int f = *flagp;
    const void* pv = phase ? i_pos : u_pos;
    int lane = threadIdx.x & 63;
    int wave = threadIdx.x >> 6;
    int vtx = blockIdx.x * 4 + wave;
    if (vtx >= (phase ? NI : NU)) return;
    const bf16_t* other = phase ? uh : ih;
    int seg = phase ? NU + vtx : vtx;
    int j0 = off[seg], j1 = off[seg + 1];
    float s1 = 0.f, s2 = 0.f, a0 = 0.f, a1 = 0.f;
    for (int cb = j0; cb < j1; cb += 64) {
        int m = j1 - cb; if (m > 64) m = 64;
        uint2 pay = make_uint2(0u, 0u);
        if (lane < m) pay = perm[cb + lane];
        unsigned px0 = (unsigned)__shfl((int)pay.x, 0, 64);
        unsigned py0 = (unsigned)__shfl((int)pay.y, 0, 64);
        int nbr0 = px0 & 0x1FFFF; int pos0 = (px0 >> 17) & 63;
        float ho0 = b2f(other[(size_t)nbr0 * 64 + lane]);
        float pv0 = ldf(pv, (size_t)pos0 * 64 + lane, f);
        for (int k = 0; k < m; ++k) {
            unsigned px1 = 0, py1 = 0; float ho1 = 0.f, pv1 = 0.f;
            if (k + 1 < m) {
                px1 = (unsigned)__shfl((int)pay.x, k + 1, 64);
                py1 = (unsigned)__shfl((int)pay.y, k + 1, 64);
                int nbr1 = px1 & 0x1FFFF; int pos1 = (px1 >> 17) & 63;
                ho1 = b2f(other[(size_t)nbr1 * 64 + lane]);
                pv1 = ldf(pv, (size_t)pos1 * 64 + lane, f);
            }
            float p1 = __half2float(__ushort_as_half((unsigned short)(py0 & 0xFFFF)));
            float p2 = __half2float(__ushort_as_half((unsigned short)(py0 >> 16)));
            a0 = fmaf(p1, ho0 + pv0, a0);
            a1 = fmaf(p2, ho0, a1);
            s1 += p1; s2 += p2;
            px0 = px1; py0 = py1; ho0 = ho1; pv0 = pv1;
        }
    }
    a0 *= 1.f / (s1 + 1e-9f);
    a1 *= 1.f / (s2 + 1e-9f);
    agg[(size_t)vtx * 128 + lane] = __float2bfloat16(a0);
    agg[(size_t)vtx * 128 + 64 + lane] = __float2bfloat16(a1);
    if (phase) {
        float r0 = 0.f, r1 = 0.f, r2 = 0.f; int c0 = 0, c1 = 0, c2 = 0;
        int k0 = off[2 * NU + vtx], k1 = off[2 * NU + vtx + 1];
        for (int cb = k0; cb < k1; cb += 64) {
            int m = k1 - cb; if (m > 64) m = 64;
            unsigned px = (lane < m) ? perm[cb + lane].x : 0u;
            for (int k = 0; k < m; ++k) {
                unsigned u = (unsigned)__shfl((int)px, k, 64);
                int row = u & 0x1FFFF; int r = (u >> 17) & 3;
                float fv = b2f(fW[(size_t)row * 64 + lane]);
                if (r == 0)      { r0 += fv; c0++; }
                else if (r == 1) { r1 += fv; c1++; }
                else             { r2 += fv; c2++; }
            }
        }
        float relv = r0 * (1.f / fmaxf((float)c0, 1.f))
                   + r1 * (1.f / fmaxf((float)c1, 1.f))
                   + r2 * (1.f / fmaxf((float)c2, 1.f));
        relb[(size_t)vtx * 64 + lane] = __float2bfloat16(relv);
    }
}

extern "C" void kernel_launch(void* const* d_in, const int* in_sizes, int n_in,
                              void* d_out, int out_size, void* d_ws, size_t ws_size,
                              hipStream_t stream) {
    const void* user_h     = d_in[0];
    const void* item_h     = d_in[1];
    const void* brand_feat = d_in[2];
    const void* cat_feat   = d_in[3];
    const void* rel_feat   = d_in[4];
    const void* Wu   = d_in[5];
    const void* Wi   = d_in[6];
    const void* Wb   = d_in[7];
    const void* Wc   = d_in[8];
    const void* Wr   = d_in[9];
    const void* Wg_u = d_in[10];
    const void* Wg_i = d_in[11];
    const void* u_pos   = d_in[12];
    const void* u_pos_k = d_in[13];
    const void* i_pos   = d_in[14];
    const void* i_pos_k = d_in[15];
    const void* basis_freq = d_in[16];
    const void* phase      = d_in[17];
    const void* Wr0 = d_in[18];
    const void* Wr1 = d_in[19];
    const void* Wr2 = d_in[20];
    const void* e_time = d_in[21];
    const int* e_iid  = (const int*)d_in[22];
    const int* e_uid  = (const int*)d_in[23];
    const int* pos_u  = (const int*)d_in[24];
    const int* pos_i  = (const int*)d_in[25];
    const int* eb_src = (const int*)d_in[26];
    const int* eb_dst = (const int*)d_in[27];
    const int* ec_src = (const int*)d_in[28];
    const int* ec_dst = (const int*)d_in[29];
    const int* er_src = (const int*)d_in[30];
    const int* er_dst = (const int*)d_in[31];

    char* base = (char*)d_ws;
    size_t off_b = 0;
    auto alloc = [&](size_t bytes) { size_t p = off_b; off_b = (off_b + bytes + 511) & ~(size_t)511; return p; };
    size_t o_flag  = alloc(512);
    size_t o_uh    = alloc((size_t)NU * 64 * 2);                 // 12.8 MB
    size_t o_ih    = alloc((size_t)NI * 64 * 2);                 // 12.8 MB
    size_t o_fW    = alloc((size_t)(NB_ + NC_ + NR_ + 64) * 64 * 2); // 7.3 MB
    size_t o_wcomb = alloc((size_t)3 * 4096 * 2);
    size_t o_deg   = alloc((size_t)SCAN_N * 4);
    size_t o_off   = alloc((size_t)SCAN_N * 4);
    size_t o_cur   = alloc((size_t)SCAN_N * 4);
    size_t o_ctot  = alloc((size_t)SCAN_NCHUNK * 4);
    size_t o_coff  = alloc((size_t)SCAN_NCHUNK * 4);
    size_t o_perm  = alloc((size_t)NPERM * 8);                   // 15.2 MB
    size_t o_agg   = alloc((size_t)(NU + 64) * 128 * 2);         // 25.6 MB (reused per phase)
    size_t o_relb  = alloc((size_t)(NI + 64) * 64 * 2);          // 12.8 MB

    int*    flagp = (int*)(base + o_flag);
    bf16_t* uh    = (bf16_t*)(base + o_uh);
    bf16_t* ih    = (bf16_t*)(base + o_ih);
    bf16_t* fW    = (bf16_t*)(base + o_fW);
    bf16_t* wcomb = (bf16_t*)(base + o_wcomb);
    int*    deg   = (int*)(base + o_deg);
    int*    offp  = (int*)(base + o_off);
    int*    cur   = (int*)(base + o_cur);
    int*    ctot  = (int*)(base + o_ctot);
    int*    coff  = (int*)(base + o_coff);
    uint2*  perm  = (uint2*)(base + o_perm);
    bf16_t* agg   = (bf16_t*)(base + o_agg);
    bf16_t* relb  = (bf16_t*)(base + o_relb);

    hipMemsetAsync(deg, 0, (size_t)SCAN_N * 4, stream);
    detect_dtype<<<1, 64, 0, stream>>>((const unsigned int*)basis_freq, flagp);

    combine_w<<<3, 256, 0, stream>>>(Wb, Wr0, Wc, Wr1, Wr, Wr2, wcomb, flagp);

    // transforms via MFMA GEMM (mode 0: bf16 out, no bias)
    gemm_n64<<<(NU + 63) / 64, 256, 0, stream>>>(user_h, 0, Wu, 0, nullptr, nullptr,
                                                 uh, 0, 0, NU, 64, flagp);
    gemm_n64<<<(NI + 63) / 64, 256, 0, stream>>>(item_h, 0, Wi, 0, nullptr, nullptr,
                                                 ih, 0, 0, NI, 64, flagp);
    gemm_n64<<<(NB_ + 63) / 64, 256, 0, stream>>>(brand_feat, 0, wcomb, 1, nullptr, nullptr,
                                                  fW, 0, 0, NB_, 64, flagp);
    gemm_n64<<<(NC_ + 63) / 64, 256, 0, stream>>>(cat_feat, 0, wcomb + 4096, 1, nullptr, nullptr,
                                                  fW + (size_t)NB_ * 64, 0, 0, NC_, 64, flagp);
    gemm_n64<<<(NR_ + 63) / 64, 256, 0, stream>>>(rel_feat, 0, wcomb + 8192, 1, nullptr, nullptr,
                                                  fW + (size_t)(NB_ + NC_) * 64, 0, 0, NR_, 64, flagp);

    hist_all<<<(NALL + 255) / 256, 256, 0, stream>>>(e_uid, e_iid, eb_dst, ec_dst, er_dst, deg);
    scan1<<<SCAN_NCHUNK, 256, 0, stream>>>(deg, offp, ctot);
    scan2<<<1, 64, 0, stream>>>(ctot, coff);
    scan3<<<SCAN_NCHUNK, 256, 0, stream>>>(offp, coff);
    hipMemcpyAsync(cur, offp, (size_t)SCAN_N * 4, hipMemcpyDeviceToDevice, stream);

    purchase_edges<<<2048, 256, 0, stream>>>(uh, ih, u_pos_k, i_pos_k, basis_freq, phase,
                                             e_time, e_uid, e_iid, pos_u, pos_i,
                                             cur, perm, flagp);
    scatter_rel_all<<<(NRELE + 255) / 256, 256, 0, stream>>>(eb_src, eb_dst, ec_src, ec_dst,
                                                             er_src, er_dst, cur, perm);

    // user phase
    gather_agg<<<VBLK, 256, 0, stream>>>(uh, ih, u_pos, i_pos, offp, perm, fW,
                                         agg, relb, flagp, 0);
    gemm_n64<<<(NU + 63) / 64, 256, 0, stream>>>(agg, 1, Wg_u, 0, user_h, nullptr,
                                                 d_out, 1, 0, NU, 128, flagp);
    // item phase (reuses agg)
    gather_agg<<<VBLK, 256, 0, stream>>>(uh, ih, u_pos, i_pos, offp, perm, fW,
                                         agg, relb, flagp, 1);
    gemm_n64<<<(NI + 63) / 64, 256, 0, stream>>>(agg, 1, Wg_i, 0, item_h, relb,
                                                 d_out, 1, NU, NI, 128, flagp);
}

// Round 2
// 716.634 us; speedup vs baseline: 1.9036x; 1.1695x over previous
//
#include <hip/hip_runtime.h>
#include <hip/hip_bf16.h>
#include <hip/hip_fp16.h>

typedef __hip_bfloat16 bf16_t;

#define NU 100000
#define NI 100000
#define NB_ 5000
#define NC_ 2000
#define NR_ 50000
#define NE 600000
#define NEB 100000
#define NEC 200000
#define NER 400000
#define NPERM (2 * NE + NEB + NEC + NER)   // 1,900,000
#define NRELE (NEB + NEC + NER)            // 700,000
#define NALL (NE + NRELE)
#define SCAN_N (2 * NU + NI + 1)
#define SCAN_CHUNK 2048
#define SCAN_NCHUNK ((SCAN_N + SCAN_CHUNK - 1) / SCAN_CHUNK)
#define VBLK ((NU + 3) / 4)                // gather blocks per phase (NU==NI)

typedef __attribute__((ext_vector_type(8))) short short8;
typedef __attribute__((ext_vector_type(4))) short short4v;
typedef __attribute__((ext_vector_type(4))) float f32x4;

__device__ __forceinline__ float b2f(bf16_t x) { return __bfloat162float(x); }
__device__ __forceinline__ float sane(float x) { return isfinite(x) ? x : 0.f; }
__device__ __forceinline__ unsigned short f2bu(float x) {
    union { bf16_t b; unsigned short u; } c; c.b = __float2bfloat16(x); return c.u;
}

// dual-dtype load/store: external float tensors are f32 or bf16, per runtime flag
__device__ __forceinline__ float ldf(const void* p, size_t i, int f32) {
    return f32 ? ((const float*)p)[i] : __bfloat162float(((const bf16_t*)p)[i]);
}
__device__ __forceinline__ void stf(void* p, size_t i, float v, int f32) {
    if (f32) ((float*)p)[i] = v;
    else     ((bf16_t*)p)[i] = __float2bfloat16(v);
}

// 4-wide packed loads (i must be a multiple of 4 elements)
__device__ __forceinline__ f32x4 bf4(const bf16_t* p) {
    short4v s = *(const short4v*)p;
    f32x4 r;
#pragma unroll
    for (int q = 0; q < 4; ++q)
        r[q] = __uint_as_float(((unsigned)(unsigned short)s[q]) << 16);
    return r;
}
__device__ __forceinline__ f32x4 ldf4(const void* p, size_t i, int f32) {
    if (f32) return *(const f32x4*)((const float*)p + i);
    return bf4((const bf16_t*)p + i);
}

// ---- dtype probe: basis_freq[0] == 1.0f exactly; f32 word = 0x3F800000 ----
__global__ void detect_dtype(const unsigned int* w, int* flag) {
    if (threadIdx.x == 0 && blockIdx.x == 0) *flag = (w[0] == 0x3F800000u) ? 1 : 0;
}

// ---- wcomb_r = W_feat_r @ Wr_r (bf16 out, internal) ----
__global__ void combine_w(const void* Wb, const void* Wr0,
                          const void* Wc, const void* Wr1,
                          const void* Wr, const void* Wr2,
                          bf16_t* out, const int* flagp) {
    int f = *flagp;
    const void* A = blockIdx.x == 0 ? Wb : (blockIdx.x == 1 ? Wc : Wr);
    const void* B = blockIdx.x == 0 ? Wr0 : (blockIdx.x == 1 ? Wr1 : Wr2);
    bf16_t* O = out + (size_t)blockIdx.x * 4096;
    for (int idx = threadIdx.x; idx < 4096; idx += blockDim.x) {
        int i = idx >> 6, j = idx & 63;
        float acc = 0.f;
        for (int k = 0; k < 64; ++k)
            acc = fmaf(ldf(A, i * 64 + k, f), ldf(B, k * 64 + j, f), acc);
        O[idx] = __float2bfloat16(acc);
    }
}

// ============================================================================
// Generic MFMA GEMM: out = act(A[M,K] @ W[K,64] + bias), K in {64,128}.
// ============================================================================
__global__ __launch_bounds__(256) void gemm_n64(
    const void* __restrict__ A, int a_internal,
    const void* __restrict__ W, int w_internal,
    const void* __restrict__ hext, const bf16_t* __restrict__ relb,
    void* __restrict__ out, int out_mode, int orow0,
    int M, int K, const int* flagp) {
    __shared__ short WL[128 * 64];   // 16 KB max (K*64 used)
    int f = *flagp;
    int a_f32 = a_internal ? 0 : f;
    int w_f32 = w_internal ? 0 : f;
    for (int i = threadIdx.x; i < K * 64; i += 256) {
        int j = i & 7, ln = (i >> 3) & 63, p = i >> 9;
        int kk4 = p >> 2, n0t = p & 3;
        int srow = kk4 * 32 + (ln >> 4) * 8 + j;
        int scol = n0t * 16 + (ln & 15);
        float wv = w_f32 ? ((const float*)W)[srow * 64 + scol]
                         : b2f(((const bf16_t*)W)[srow * 64 + scol]);
        WL[i] = (short)f2bu(wv);
    }
    __syncthreads();
    int lane = threadIdx.x & 63;
    int wv = threadIdx.x >> 6;
    int q = lane >> 4, nl = lane & 15;
    int m0 = blockIdx.x * 64 + wv * 16;
    if (m0 >= M) return;
    int arow = m0 + nl; if (arow >= M) arow = M - 1;
    f32x4 acc[4];
#pragma unroll
    for (int t = 0; t < 4; ++t) acc[t] = (f32x4){0.f, 0.f, 0.f, 0.f};
    int KK = K >> 5;
    for (int kk4 = 0; kk4 < KK; ++kk4) {
        short8 af;
        size_t abase = (size_t)arow * K + kk4 * 32 + q * 8;
        if (a_f32) {
            const f32x4* ap = (const f32x4*)((const float*)A + abase);
            f32x4 x0 = ap[0], x1 = ap[1];
#pragma unroll
            for (int j = 0; j < 4; ++j) {
                af[j] = (short)f2bu(x0[j]);
                af[4 + j] = (short)f2bu(x1[j]);
            }
        } else {
            af = *(const short8*)((const bf16_t*)A + abase);
        }
#pragma unroll
        for (int n0t = 0; n0t < 4; ++n0t) {
            short8 bfr = *(const short8*)&WL[(((kk4 << 2) + n0t) * 64 + lane) * 8];
            acc[n0t] = __builtin_amdgcn_mfma_f32_16x16x32_bf16(af, bfr, acc[n0t], 0, 0, 0);
        }
    }
#pragma unroll
    for (int n0t = 0; n0t < 4; ++n0t) {
#pragma unroll
        for (int r = 0; r < 4; ++r) {
            int row = m0 + q * 4 + r;
            if (row >= M) continue;
            int col = n0t * 16 + nl;
            float v = acc[n0t][r];
            if (out_mode == 1) {
                v += ldf(hext, (size_t)row * 64 + col, f);
                if (relb) v += b2f(relb[(size_t)row * 64 + col]);
                v = v > 0.f ? v : expm1f(v);
                stf(out, (size_t)(row + orow0) * 64 + col, sane(v), f);
            } else {
                ((bf16_t*)out)[(size_t)row * 64 + col] = __float2bfloat16(v);
            }
        }
    }
}

// ---- one-launch degree histogram over all edge sets ----
__global__ __launch_bounds__(256) void hist_all(
    const int* __restrict__ e_uid, const int* __restrict__ e_iid,
    const int* __restrict__ eb_dst, const int* __restrict__ ec_dst,
    const int* __restrict__ er_dst, int* __restrict__ deg) {
    int t = blockIdx.x * blockDim.x + threadIdx.x;
    if (t < NE) {
        atomicAdd(deg + e_uid[t], 1);
        atomicAdd(deg + NU + e_iid[t], 1);
    } else if (t < NE + NEB) {
        atomicAdd(deg + 2 * NU + eb_dst[t - NE], 1);
    } else if (t < NE + NEB + NEC) {
        atomicAdd(deg + 2 * NU + ec_dst[t - NE - NEB], 1);
    } else if (t < NALL) {
        atomicAdd(deg + 2 * NU + er_dst[t - NE - NEB - NEC], 1);
    }
}

// ---- exclusive scan over SCAN_N ints ----
__global__ __launch_bounds__(256) void scan1(const int* __restrict__ deg,
                                             int* __restrict__ off,
                                             int* __restrict__ ctot) {
    __shared__ int part[256];
    int base = blockIdx.x * SCAN_CHUNK + threadIdx.x * 8;
    int v[8]; int s = 0;
#pragma unroll
    for (int k = 0; k < 8; ++k) {
        int idx = base + k;
        v[k] = s;
        s += (idx < SCAN_N) ? deg[idx] : 0;
    }
    part[threadIdx.x] = s;
    __syncthreads();
    for (int o = 1; o < 256; o <<= 1) {
        int t = (threadIdx.x >= o) ? part[threadIdx.x - o] : 0;
        __syncthreads();
        part[threadIdx.x] += t;
        __syncthreads();
    }
    int texc = (threadIdx.x == 0) ? 0 : part[threadIdx.x - 1];
#pragma unroll
    for (int k = 0; k < 8; ++k) {
        int idx = base + k;
        if (idx < SCAN_N) off[idx] = texc + v[k];
    }
    if (threadIdx.x == 255) ctot[blockIdx.x] = part[255];
}
__global__ void scan2(const int* __restrict__ ctot, int* __restrict__ coff) {
    if (threadIdx.x == 0 && blockIdx.x == 0) {
        int s = 0;
        for (int i = 0; i < SCAN_NCHUNK; ++i) { coff[i] = s; s += ctot[i]; }
    }
}
__global__ __launch_bounds__(256) void scan3(int* __restrict__ off,
                                             const int* __restrict__ coff) {
    int add = coff[blockIdx.x];
    int base = blockIdx.x * SCAN_CHUNK + threadIdx.x;
#pragma unroll
    for (int k = 0; k < 8; ++k) {
        int idx = base + k * 256;
        if (idx < SCAN_N) off[idx] += add;
    }
}

// ---- 4 edges per wave, 16 lanes each (lane covers 4 of 64 elements) ----
// payload: {nbr | pos<<17,  f16(p_long) | f16(p_short)<<16}
// One wave load instruction fetches rows for 4 edges -> 4x MLP per slot;
// dot reduction is a 4-step butterfly within each 16-lane group.
__global__ __launch_bounds__(256) void purchase_edges(
    const bf16_t* __restrict__ uh, const bf16_t* __restrict__ ih,
    const void* __restrict__ u_pos_k, const void* __restrict__ i_pos_k,
    const void* __restrict__ basis_freq, const void* __restrict__ phase,
    const void* __restrict__ e_time,
    const int* __restrict__ e_uid, const int* __restrict__ e_iid,
    const int* __restrict__ pos_u, const int* __restrict__ pos_i,
    int* __restrict__ cur, uint2* __restrict__ perm, const int* flagp) {
    int f = *flagp;
    int lane = threadIdx.x & 63;
    int g = lane >> 4, l = lane & 15;
    f32x4 bfv = ldf4(basis_freq, l * 4, f);
    f32x4 phv = ldf4(phase, l * 4, f);
    int w = (blockIdx.x * blockDim.x + threadIdx.x) >> 6;
    int nw = (gridDim.x * blockDim.x) >> 6;
    for (int eb = w; eb < NE / 4; eb += nw) {
        int e = eb * 4 + g;                 // NE % 4 == 0, always in range
        int uid = e_uid[e], iid = e_iid[e], pu = pos_u[e], pi = pos_i[e];
        float t = ldf(e_time, e, f);
        f32x4 hu = bf4(uh + (size_t)uid * 64 + l * 4);
        f32x4 hi = bf4(ih + (size_t)iid * 64 + l * 4);
        f32x4 pku = ldf4(u_pos_k, (size_t)pu * 64 + l * 4, f);
        f32x4 pki = ldf4(i_pos_k, (size_t)pi * 64 + l * 4, f);
        float d_lu = 0.f, d_sh = 0.f, d_li = 0.f;
#pragma unroll
        for (int q = 0; q < 4; ++q) {
            float te = __cosf(fmaf(t, bfv[q], phv[q]));
            d_lu = fmaf(hi[q] + pku[q] + te, hu[q], d_lu);
            d_sh = fmaf(hi[q], hu[q], d_sh);
            d_li = fmaf(hu[q] + pki[q] + te, hi[q], d_li);
        }
#pragma unroll
        for (int o = 1; o < 16; o <<= 1) {
            d_lu += __shfl_xor(d_lu, o, 64);
            d_sh += __shfl_xor(d_sh, o, 64);
            d_li += __shfl_xor(d_li, o, 64);
        }
        if (l == 0) {
            float p_lu = __expf(fminf(d_lu * 0.125f, 10.f));   // clamp protects f16 pack
            float p_sh = __expf(fminf(d_sh * 0.125f, 10.f));
            float p_li = __expf(fminf(d_li * 0.125f, 10.f));
            unsigned pkt_u = (unsigned)__half_as_ushort(__float2half(p_lu))
                           | ((unsigned)__half_as_ushort(__float2half(p_sh)) << 16);
            unsigned pkt_i = (unsigned)__half_as_ushort(__float2half(p_li))
                           | ((unsigned)__half_as_ushort(__float2half(p_sh)) << 16);
            int s1 = atomicAdd(cur + uid, 1);
            perm[s1] = make_uint2((unsigned)iid | ((unsigned)pu << 17), pkt_u);
            int s2 = atomicAdd(cur + NU + iid, 1);
            perm[s2] = make_uint2((unsigned)uid | ((unsigned)pi << 17), pkt_i);
        }
    }
}

// ---- relation edge payload scatter (thread per edge) ----
__global__ __launch_bounds__(256) void scatter_rel_all(
    const int* __restrict__ eb_src, const int* __restrict__ eb_dst,
    const int* __restrict__ ec_src, const int* __restrict__ ec_dst,
    const int* __restrict__ er_src, const int* __restrict__ er_dst,
    int* __restrict__ cur, uint2* __restrict__ perm) {
    int t = blockIdx.x * blockDim.x + threadIdx.x;
    if (t < NEB) {
        int p = atomicAdd(cur + 2 * NU + eb_dst[t], 1);
        perm[p] = make_uint2((unsigned)eb_src[t], 0u);
    } else if (t < NEB + NEC) {
        int e = t - NEB;
        int p = atomicAdd(cur + 2 * NU + ec_dst[e], 1);
        perm[p] = make_uint2((unsigned)(ec_src[e] + NB_) | (1u << 17), 0u);
    } else if (t < NRELE) {
        int e = t - NEB - NEC;
        int p = atomicAdd(cur + 2 * NU + er_dst[e], 1);
        perm[p] = make_uint2((unsigned)(er_src[e] + NB_ + NC_) | (2u << 17), 0u);
    }
}

// ---- gather: 1 wave per vertex; 4 neighbors concurrent in 16-lane groups ----
// Each lane accumulates 4 of the 64 elements; group partials combined once
// per vertex via xor-16/32 shuffles. Zero-padded payloads give p1=p2=0, so
// no validity guards needed in the weighted sums.
__global__ __launch_bounds__(256) void gather_agg(
    const bf16_t* __restrict__ uh, const bf16_t* __restrict__ ih,
    const void* __restrict__ u_pos, const void* __restrict__ i_pos,
    const int* __restrict__ off, const uint2* __restrict__ perm,
    const bf16_t* __restrict__ fW,
    bf16_t* __restrict__ agg, bf16_t* __restrict__ relb,
    const int* flagp, int phase) {            // phase 0 = user, 1 = item
    int f = *flagp;
    const void* pv = phase ? i_pos : u_pos;
    int lane = threadIdx.x & 63;
    int g = lane >> 4, l = lane & 15;
    int wave = threadIdx.x >> 6;
    int vtx = blockIdx.x * 4 + wave;
    if (vtx >= (phase ? NI : NU)) return;
    const bf16_t* other = phase ? uh : ih;
    int seg = phase ? NU + vtx : vtx;
    int j0 = off[seg], j1 = off[seg + 1];
    float s1 = 0.f, s2 = 0.f;
    f32x4 a0 = (f32x4){0.f, 0.f, 0.f, 0.f}, a1 = a0;
    for (int cb = j0; cb < j1; cb += 64) {
        int m = j1 - cb; if (m > 64) m = 64;
        uint2 pay = make_uint2(0u, 0u);
        if (lane < m) pay = perm[cb + lane];
        // pipeline stage 0 (neighbors g, g+4, ...)
        unsigned px0 = (unsigned)__shfl((int)pay.x, g, 64);
        unsigned py0 = (unsigned)__shfl((int)pay.y, g, 64);
        f32x4 ho0 = bf4(other + (size_t)(px0 & 0x1FFFF) * 64 + l * 4);
        f32x4 pv0 = ldf4(pv, (size_t)((px0 >> 17) & 63) * 64 + l * 4, f);
        for (int k = 0; k < m; k += 4) {
            unsigned px1 = 0, py1 = 0;
            f32x4 ho1 = (f32x4){0.f, 0.f, 0.f, 0.f}, pv1 = ho1;
            if (k + 4 < m) {
                px1 = (unsigned)__shfl((int)pay.x, k + 4 + g, 64);
                py1 = (unsigned)__shfl((int)pay.y, k + 4 + g, 64);
                ho1 = bf4(other + (size_t)(px1 & 0x1FFFF) * 64 + l * 4);
                pv1 = ldf4(pv, (size_t)((px1 >> 17) & 63) * 64 + l * 4, f);
            }
            float p1 = __half2float(__ushort_as_half((unsigned short)(py0 & 0xFFFF)));
            float p2 = __half2float(__ushort_as_half((unsigned short)(py0 >> 16)));
#pragma unroll
            for (int q = 0; q < 4; ++q) {
                a0[q] = fmaf(p1, ho0[q] + pv0[q], a0[q]);
                a1[q] = fmaf(p2, ho0[q], a1[q]);
            }
            s1 += p1; s2 += p2;
            px0 = px1; py0 = py1; ho0 = ho1; pv0 = pv1;
        }
    }
    // combine the 4 group partials
#pragma unroll
    for (int o = 16; o < 64; o <<= 1) {
#pragma unroll
        for (int q = 0; q < 4; ++q) {
            a0[q] += __shfl_xor(a0[q], o, 64);
            a1[q] += __shfl_xor(a1[q], o, 64);
        }
        s1 += __shfl_xor(s1, o, 64);
        s2 += __shfl_xor(s2, o, 64);
    }
    float inv1 = 1.f / (s1 + 1e-9f), inv2 = 1.f / (s2 + 1e-9f);
    if (g == 0) {
        short4v o0;
#pragma unroll
        for (int q = 0; q < 4; ++q) o0[q] = (short)f2bu(a0[q] * inv1);
        *(short4v*)(agg + (size_t)vtx * 128 + l * 4) = o0;
    } else if (g == 1) {
        short4v o1;
#pragma unroll
        for (int q = 0; q < 4; ++q) o1[q] = (short)f2bu(a1[q] * inv2);
        *(short4v*)(agg + (size_t)vtx * 128 + 64 + l * 4) = o1;
    }
    if (phase) {
        f32x4 r0 = (f32x4){0.f, 0.f, 0.f, 0.f}, r1 = r0, r2 = r0;
        int c0 = 0, c1 = 0, c2 = 0;
        int k0 = off[2 * NU + vtx], k1 = off[2 * NU + vtx + 1];
        for (int cb = k0; cb < k1; cb += 64) {
            int m = k1 - cb; if (m > 64) m = 64;
            unsigned px = (lane < m) ? perm[cb + lane].x : 0u;
            // stage 0
            unsigned u0 = (unsigned)__shfl((int)px, g, 64);
            f32x4 fv0 = bf4(fW + (size_t)(u0 & 0x1FFFF) * 64 + l * 4);
            for (int k = 0; k < m; k += 4) {
                unsigned u1 = 0;
                f32x4 fv1 = (f32x4){0.f, 0.f, 0.f, 0.f};
                if (k + 4 < m) {
                    u1 = (unsigned)__shfl((int)px, k + 4 + g, 64);
                    fv1 = bf4(fW + (size_t)(u1 & 0x1FFFF) * 64 + l * 4);
                }
                if (k + g < m) {
                    int r = (u0 >> 17) & 3;
                    if (r == 0) {
#pragma unroll
                        for (int q = 0; q < 4; ++q) r0[q] += fv0[q];
                        c0++;
                    } else if (r == 1) {
#pragma unroll
                        for (int q = 0; q < 4; ++q) r1[q] += fv0[q];
                        c1++;
                    } else {
#pragma unroll
                        for (int q = 0; q < 4; ++q) r2[q] += fv0[q];
                        c2++;
                    }
                }
                u0 = u1; fv0 = fv1;
            }
        }
#pragma unroll
        for (int o = 16; o < 64; o <<= 1) {
#pragma unroll
            for (int q = 0; q < 4; ++q) {
                r0[q] += __shfl_xor(r0[q], o, 64);
                r1[q] += __shfl_xor(r1[q], o, 64);
                r2[q] += __shfl_xor(r2[q], o, 64);
            }
            c0 += __shfl_xor(c0, o, 64);
            c1 += __shfl_xor(c1, o, 64);
            c2 += __shfl_xor(c2, o, 64);
        }
        float w0 = 1.f / fmaxf((float)c0, 1.f);
        float w1 = 1.f / fmaxf((float)c1, 1.f);
        float w2 = 1.f / fmaxf((float)c2, 1.f);
        if (g == 0) {
            short4v ro;
#pragma unroll
            for (int q = 0; q < 4; ++q)
                ro[q] = (short)f2bu(r0[q] * w0 + r1[q] * w1 + r2[q] * w2);
            *(short4v*)(relb + (size_t)vtx * 64 + l * 4) = ro;
        }
    }
}

extern "C" void kernel_launch(void* const* d_in, const int* in_sizes, int n_in,
                              void* d_out, int out_size, void* d_ws, size_t ws_size,
                              hipStream_t stream) {
    const void* user_h     = d_in[0];
    const void* item_h     = d_in[1];
    const void* brand_feat = d_in[2];
    const void* cat_feat   = d_in[3];
    const void* rel_feat   = d_in[4];
    const void* Wu   = d_in[5];
    const void* Wi   = d_in[6];
    const void* Wb   = d_in[7];
    const void* Wc   = d_in[8];
    const void* Wr   = d_in[9];
    const void* Wg_u = d_in[10];
    const void* Wg_i = d_in[11];
    const void* u_pos   = d_in[12];
    const void* u_pos_k = d_in[13];
    const void* i_pos   = d_in[14];
    const void* i_pos_k = d_in[15];
    const void* basis_freq = d_in[16];
    const void* phase      = d_in[17];
    const void* Wr0 = d_in[18];
    const void* Wr1 = d_in[19];
    const void* Wr2 = d_in[20];
    const void* e_time = d_in[21];
    const int* e_iid  = (const int*)d_in[22];
    const int* e_uid  = (const int*)d_in[23];
    const int* pos_u  = (const int*)d_in[24];
    const int* pos_i  = (const int*)d_in[25];
    const int* eb_src = (const int*)d_in[26];
    const int* eb_dst = (const int*)d_in[27];
    const int* ec_src = (const int*)d_in[28];
    const int* ec_dst = (const int*)d_in[29];
    const int* er_src = (const int*)d_in[30];
    const int* er_dst = (const int*)d_in[31];

    char* base = (char*)d_ws;
    size_t off_b = 0;
    auto alloc = [&](size_t bytes) { size_t p = off_b; off_b = (off_b + bytes + 511) & ~(size_t)511; return p; };
    size_t o_flag  = alloc(512);
    size_t o_uh    = alloc((size_t)NU * 64 * 2);                 // 12.8 MB
    size_t o_ih    = alloc((size_t)NI * 64 * 2);                 // 12.8 MB
    size_t o_fW    = alloc((size_t)(NB_ + NC_ + NR_ + 64) * 64 * 2); // 7.3 MB
    size_t o_wcomb = alloc((size_t)3 * 4096 * 2);
    size_t o_deg   = alloc((size_t)SCAN_N * 4);
    size_t o_off   = alloc((size_t)SCAN_N * 4);
    size_t o_cur   = alloc((size_t)SCAN_N * 4);
    size_t o_ctot  = alloc((size_t)SCAN_NCHUNK * 4);
    size_t o_coff  = alloc((size_t)SCAN_NCHUNK * 4);
    size_t o_perm  = alloc((size_t)NPERM * 8);                   // 15.2 MB
    size_t o_agg   = alloc((size_t)(NU + 64) * 128 * 2);         // 25.6 MB (reused per phase)
    size_t o_relb  = alloc((size_t)(NI + 64) * 64 * 2);          // 12.8 MB

    int*    flagp = (int*)(base + o_flag);
    bf16_t* uh    = (bf16_t*)(base + o_uh);
    bf16_t* ih    = (bf16_t*)(base + o_ih);
    bf16_t* fW    = (bf16_t*)(base + o_fW);
    bf16_t* wcomb = (bf16_t*)(base + o_wcomb);
    int*    deg   = (int*)(base + o_deg);
    int*    offp  = (int*)(base + o_off);
    int*    cur   = (int*)(base + o_cur);
    int*    ctot  = (int*)(base + o_ctot);
    int*    coff  = (int*)(base + o_coff);
    uint2*  perm  = (uint2*)(base + o_perm);
    bf16_t* agg   = (bf16_t*)(base + o_agg);
    bf16_t* relb  = (bf16_t*)(base + o_relb);

    hipMemsetAsync(deg, 0, (size_t)SCAN_N * 4, stream);
    detect_dtype<<<1, 64, 0, stream>>>((const unsigned int*)basis_freq, flagp);

    combine_w<<<3, 256, 0, stream>>>(Wb, Wr0, Wc, Wr1, Wr, Wr2, wcomb, flagp);

    // transforms via MFMA GEMM (mode 0: bf16 out, no bias)
    gemm_n64<<<(NU + 63) / 64, 256, 0, stream>>>(user_h, 0, Wu, 0, nullptr, nullptr,
                                                 uh, 0, 0, NU, 64, flagp);
    gemm_n64<<<(NI + 63) / 64, 256, 0, stream>>>(item_h, 0, Wi, 0, nullptr, nullptr,
                                                 ih, 0, 0, NI, 64, flagp);
    gemm_n64<<<(NB_ + 63) / 64, 256, 0, stream>>>(brand_feat, 0, wcomb, 1, nullptr, nullptr,
                                                  fW, 0, 0, NB_, 64, flagp);
    gemm_n64<<<(NC_ + 63) / 64, 256, 0, stream>>>(cat_feat, 0, wcomb + 4096, 1, nullptr, nullptr,
                                                  fW + (size_t)NB_ * 64, 0, 0, NC_, 64, flagp);
    gemm_n64<<<(NR_ + 63) / 64, 256, 0, stream>>>(rel_feat, 0, wcomb + 8192, 1, nullptr, nullptr,
                                                  fW + (size_t)(NB_ + NC_) * 64, 0, 0, NR_, 64, flagp);

    hist_all<<<(NALL + 255) / 256, 256, 0, stream>>>(e_uid, e_iid, eb_dst, ec_dst, er_dst, deg);
    scan1<<<SCAN_NCHUNK, 256, 0, stream>>>(deg, offp, ctot);
    scan2<<<1, 64, 0, stream>>>(ctot, coff);
    scan3<<<SCAN_NCHUNK, 256, 0, stream>>>(offp, coff);
    hipMemcpyAsync(cur, offp, (size_t)SCAN_N * 4, hipMemcpyDeviceToDevice, stream);

    purchase_edges<<<2048, 256, 0, stream>>>(uh, ih, u_pos_k, i_pos_k, basis_freq, phase,
                                             e_time, e_uid, e_iid, pos_u, pos_i,
                                             cur, perm, flagp);
    scatter_rel_all<<<(NRELE + 255) / 256, 256, 0, stream>>>(eb_src, eb_dst, ec_src, ec_dst,
                                                             er_src, er_dst, cur, perm);

    // user phase
    gather_agg<<<VBLK, 256, 0, stream>>>(uh, ih, u_pos, i_pos, offp, perm, fW,
                                         agg, relb, flagp, 0);
    gemm_n64<<<(NU + 63) / 64, 256, 0, stream>>>(agg, 1, Wg_u, 0, user_h, nullptr,
                                                 d_out, 1, 0, NU, 128, flagp);
    // item phase (reuses agg)
    gather_agg<<<VBLK, 256, 0, stream>>>(uh, ih, u_pos, i_pos, offp, perm, fW,
                                         agg, relb, flagp, 1);
    gemm_n64<<<(NI + 63) / 64, 256, 0, stream>>>(agg, 1, Wg_i, 0, item_h, relb,
                                                 d_out, 1, NU, NI, 128, flagp);
}